// Round 4
// baseline (1028.431 us; speedup 1.0000x reference)
//
#include <hip/hip_runtime.h>
#include <math.h>

using short8 = __attribute__((ext_vector_type(8))) short;
using f32x16 = __attribute__((ext_vector_type(16))) float;

// ---------------- workspace byte offsets ----------------
static const size_t B_QHI = 0;                  // h1q hi [(qy*19+qx)][b][ci] bf16
static const size_t B_QLO = 47316992;
static const size_t B_WHI = 94633984;           // w2t [k][c][ci] bf16 hi/lo
static const size_t B_WLO = 105250816;
static const size_t B_H2  = 115867648;          // h2t [c*36+p][b] fp32
static const size_t B_END = 125304832;
// routing buffers alias h1q region (dead after conv2) — float offsets
static const size_t F_UT = 0;            // [1152][8][256]
static const size_t F_SP = 2359296;      // [72][160][256]
static const size_t F_OB = 5308416;      // [160][256]
static const size_t F_BS = 5349376;      // [10][1152][16]
static const size_t F_PR = 5533696;      // [10][1152][16]

__device__ __forceinline__ unsigned short bf16_rne(float v) {
    unsigned int u = __builtin_bit_cast(unsigned int, v);
    u += 0x7FFFu + ((u >> 16) & 1u);
    return (unsigned short)(u >> 16);
}
__device__ __forceinline__ float bf16_tof(unsigned short h) {
    unsigned int u = ((unsigned int)h) << 16;
    return __builtin_bit_cast(float, u);
}

// async global->LDS, 16B per lane, dest = uniform base + lane*16
__device__ __forceinline__ void gll16(const unsigned short* g, unsigned short* l) {
    __builtin_amdgcn_global_load_lds(
        (const __attribute__((address_space(1))) unsigned int*)(uintptr_t)g,
        (__attribute__((address_space(3))) unsigned int*)(uintptr_t)l,
        16, 0, 0);
}

// ---------------- conv1: grid (b, x-half), thread = c ----------------------
// row-register reuse: 20 x-values per (oy,ky) serve all 12 ox (108 FMA / 20 reads)
__global__ __launch_bounds__(256) void conv1_kernel(
        const float* __restrict__ x, const float* __restrict__ w1,
        const float* __restrict__ b1,
        unsigned short* __restrict__ qhi, unsigned short* __restrict__ qlo) {
    int b  = blockIdx.x;
    int xh = blockIdx.y;                 // 0: ox 0..9, 1: ox 10..18
    int c  = threadIdx.x;
    __shared__ float xs[28][20];
    for (int i = c; i < 560; i += 256) {
        int row = i / 20, cl = i - row * 20, gc = xh * 10 + cl;
        xs[row][cl] = (gc < 28) ? x[(size_t)b*784 + row*28 + gc] : 0.f;
    }
    float wr[81];
    #pragma unroll
    for (int k = 0; k < 81; ++k) wr[k] = w1[c*81 + k];
    float bias = b1[c];
    __syncthreads();
    for (int oy = 0; oy < 19; ++oy) {
        float acc[12];
        #pragma unroll
        for (int e = 0; e < 12; ++e) acc[e] = 0.f;
        #pragma unroll
        for (int ky = 0; ky < 9; ++ky) {
            float xr[20];
            #pragma unroll
            for (int i = 0; i < 20; ++i) xr[i] = xs[oy + ky][i];
            #pragma unroll
            for (int kx = 0; kx < 9; ++kx) {
                float wv_ = wr[ky*9 + kx];
                #pragma unroll
                for (int e = 0; e < 12; ++e)
                    acc[e] = fmaf(xr[e + kx], wv_, acc[e]);
            }
        }
        #pragma unroll
        for (int e = 0; e < 12; ++e) {
            int ox = xh*10 + e;
            if (e < 10 && ox < 19) {
                float v = fmaxf(bias + acc[e], 0.f);
                unsigned short hi = bf16_rne(v);
                unsigned short lo = bf16_rne(v - bf16_tof(hi));
                size_t o = ((size_t)(oy*19 + ox)*256 + b)*256 + c;
                qhi[o] = hi; qlo[o] = lo;
            }
        }
    }
}

// ---------------- w2 transpose+split: [c][ci][81] -> [k][c][ci] hi/lo -------
__global__ __launch_bounds__(256) void w2t_kernel(
        const float* __restrict__ w2,
        unsigned short* __restrict__ whi, unsigned short* __restrict__ wlo) {
    int c    = blockIdx.x;
    int half = blockIdx.y;
    int t = threadIdx.x;
    __shared__ float buf[128*81];
    const float* src = w2 + (size_t)c*20736 + (size_t)half*128*81;
    for (int i = t; i < 128*81; i += 256) buf[i] = src[i];
    __syncthreads();
    int kk = t >> 7, cil = t & 127;
    for (int k2 = 0; k2 < 41; ++k2) {
        int k = k2*2 + kk;
        if (k < 81) {
            float v = buf[cil*81 + k];
            unsigned short hi = bf16_rne(v);
            unsigned short lo = bf16_rne(v - bf16_tof(hi));
            size_t o = ((size_t)k*256 + c)*256 + half*128 + cil;
            whi[o] = hi; wlo[o] = lo;
        }
    }
}

// ---------------- conv2: 32x32x16 MFMA, producer/consumer waves -------------
// block = 32b x 3ox (oy,oxh fixed) x 32c; 768 blocks = 3/CU. wave0 = consumer
// (all frags->regs, 81 MFMA/step), wave1 = producer (44 global_load_lds/step).
// LDS rows are 1KB = 64 chunks of 16B; chunk' = (2b+h)^((b>>2)&3) swizzle
// applied on the pre-swizzled per-lane GLOBAL source (LDS dest stays linear).
__global__ __launch_bounds__(128, 2) void conv2_mfma(
        const unsigned short* __restrict__ qhi, const unsigned short* __restrict__ qlo,
        const unsigned short* __restrict__ whi, const unsigned short* __restrict__ wlo,
        const float* __restrict__ b2, float* __restrict__ h2t) {
    int bx = blockIdx.x;                 // 0..95 : ((bt*6+oy)*2+oxh)
    int oxh = bx & 1;
    int tmp = bx >> 1;
    int oy = tmp % 6, bt = tmp / 6;
    int cg = blockIdx.y;                 // 0..7
    int qx0 = oxh * 6;
    int t = threadIdx.x;
    int wv = t >> 6, l = t & 63;

    __shared__ unsigned short Ah[13*512], Al[13*512];   // 13 qx-rows x 1KB
    __shared__ unsigned short Bh[9*512],  Bl[9*512];    // 9 kx-rows x 1KB
    // total 45056 B -> exactly 3 blocks/CU

    // producer: per-lane source chunk decode (inverse of read swizzle)
    int chunk = l ^ ((l >> 3) & 3);
    size_t lane_off = ((size_t)(chunk >> 1) << 8) + (size_t)(chunk & 1) * 8;
    // consumer: swizzled chunk position for fragment reads
    int cpos = (2*(l & 31) + (l >> 5)) ^ ((l >> 2) & 3);

    f32x16 acc[3];
    #pragma unroll
    for (int i = 0; i < 3; ++i)
        #pragma unroll
        for (int r = 0; r < 16; ++r) acc[i][r] = 0.f;

    if (wv == 1) {   // stage step 0 (ky=0, cis=0)
        const unsigned short* aBh = qhi + (((size_t)((oy*2)*19 + qx0)*256 + bt*32) << 8) + lane_off;
        const unsigned short* aBl = qlo + (((size_t)((oy*2)*19 + qx0)*256 + bt*32) << 8) + lane_off;
        #pragma unroll
        for (int q = 0; q < 13; ++q) {
            gll16(aBh + ((size_t)q << 16), Ah + q*512);
            gll16(aBl + ((size_t)q << 16), Al + q*512);
        }
        const unsigned short* bBh = whi + (((size_t)(0*256) + cg*32 << 8)) + lane_off;
        const unsigned short* bBl = wlo + (((size_t)(0*256) + cg*32 << 8)) + lane_off;
        #pragma unroll
        for (int kx = 0; kx < 9; ++kx) {
            gll16(bBh + ((size_t)kx << 16), Bh + kx*512);
            gll16(bBl + ((size_t)kx << 16), Bl + kx*512);
        }
    }
    __syncthreads();

    #pragma unroll 1
    for (int step = 0; step < 144; ++step) {
        short8 afh[13], afl[13], bfh[9], bfl[9];
        if (wv == 0) {
            #pragma unroll
            for (int q = 0; q < 13; ++q) {
                afh[q] = *(const short8*)(Ah + q*512 + cpos*8);
                afl[q] = *(const short8*)(Al + q*512 + cpos*8);
            }
            #pragma unroll
            for (int kx = 0; kx < 9; ++kx) {
                bfh[kx] = *(const short8*)(Bh + kx*512 + cpos*8);
                bfl[kx] = *(const short8*)(Bl + kx*512 + cpos*8);
            }
        }
        __syncthreads();     // consumer reads done (lgkmcnt drained at barrier)
        if (wv == 1 && step < 143) {
            int ns = step + 1;
            int ky1 = ns >> 4, cis1 = ns & 15;
            size_t loff = lane_off + (size_t)cis1 * 16;
            const unsigned short* aBh = qhi + (((size_t)((oy*2 + ky1)*19 + qx0)*256 + bt*32) << 8) + loff;
            const unsigned short* aBl = qlo + (((size_t)((oy*2 + ky1)*19 + qx0)*256 + bt*32) << 8) + loff;
            #pragma unroll
            for (int q = 0; q < 13; ++q) {
                gll16(aBh + ((size_t)q << 16), Ah + q*512);
                gll16(aBl + ((size_t)q << 16), Al + q*512);
            }
            const unsigned short* bBh = whi + (((size_t)(ky1*9)*256 + cg*32) << 8) + loff;
            const unsigned short* bBl = wlo + (((size_t)(ky1*9)*256 + cg*32) << 8) + loff;
            #pragma unroll
            for (int kx = 0; kx < 9; ++kx) {
                gll16(bBh + ((size_t)kx << 16), Bh + kx*512);
                gll16(bBl + ((size_t)kx << 16), Bl + kx*512);
            }
        }
        if (wv == 0) {
            __builtin_amdgcn_s_setprio(1);
            #pragma unroll
            for (int kx = 0; kx < 9; ++kx) {
                #pragma unroll
                for (int oxl = 0; oxl < 3; ++oxl) {
                    int ql = 2*oxl + kx;
                    acc[oxl] = __builtin_amdgcn_mfma_f32_32x32x16_bf16(afh[ql], bfh[kx], acc[oxl], 0, 0, 0);
                    acc[oxl] = __builtin_amdgcn_mfma_f32_32x32x16_bf16(afh[ql], bfl[kx], acc[oxl], 0, 0, 0);
                    acc[oxl] = __builtin_amdgcn_mfma_f32_32x32x16_bf16(afl[ql], bfh[kx], acc[oxl], 0, 0, 0);
                }
            }
            __builtin_amdgcn_s_setprio(0);
        }
        __syncthreads();     // producer's vmcnt(0) drain covered by MFMA phase
    }

    // ---- epilogue: transpose via LDS (alias Ah), coalesced float stores ----
    float* ebuf = (float*)Ah;            // [3][32][33] = 12672 B <= 13312
    if (wv == 0) {
        float bv = b2[cg*32 + (l & 31)];
        #pragma unroll
        for (int oxl = 0; oxl < 3; ++oxl)
            #pragma unroll
            for (int r = 0; r < 16; ++r) {
                int row = (r & 3) + 8*(r >> 2) + 4*(l >> 5);   // b-local
                ebuf[oxl*1056 + row*33 + (l & 31)] = acc[oxl][r] + bv;
            }
    }
    __syncthreads();
    #pragma unroll 1
    for (int pass = 0; pass < 24; ++pass) {
        int row_id = pass*4 + (t >> 5);          // 0..95 = oxl*32 + c
        int oxl = row_id >> 5, c = row_id & 31;
        float v = ebuf[oxl*1056 + (t & 31)*33 + c];
        int p = oy*6 + oxh*3 + oxl;
        h2t[(size_t)((cg*32 + c)*36 + p)*256 + bt*32 + (t & 31)] = v;
    }
}

// -------- primary squash: h2t[n*8+j][b] -> ut[n][j][b], fully coalesced -----
__global__ __launch_bounds__(256) void squash_t_kernel(
        const float* __restrict__ h2t, float* __restrict__ ut) {
    int n = blockIdx.x;       // 0..1151
    int b = threadIdx.x;      // 0..255
    float v[8];
    float sq = 0.f;
    #pragma unroll
    for (int j = 0; j < 8; ++j) {
        v[j] = h2t[(size_t)(n*8 + j)*256 + b];
        sq = fmaf(v[j], v[j], sq);
    }
    float sc = sq / (1.0f + sq);   // primary squash: NO /sqrt
    #pragma unroll
    for (int j = 0; j < 8; ++j)
        ut[((size_t)n*8 + j)*256 + b] = sc * v[j];
}

// -------- s partials: s[c,i,b] = sum_n probs[c,n,i] * sum_j W*ut ------------
__global__ __launch_bounds__(256) void spart_kernel(
        const float* __restrict__ ut, const float* __restrict__ W,
        const float* __restrict__ probs, float* __restrict__ sp, int uniform) {
    int ch = blockIdx.x;      // 0..71 (n-chunks of 16)
    int c  = blockIdx.y;      // 0..9
    int t  = threadIdx.x;     // b
    float acc[16];
    #pragma unroll
    for (int i = 0; i < 16; ++i) acc[i] = 0.0f;
    int n0 = ch * 16;
    for (int nn = 0; nn < 16; ++nn) {
        int n = n0 + nn;
        float utv[8];
        #pragma unroll
        for (int j = 0; j < 8; ++j) utv[j] = ut[((size_t)n*8 + j)*256 + t];
        const float* Wr = W + ((size_t)c*1152 + n)*128;
        const float* pr = probs + ((size_t)c*1152 + n)*16;
        #pragma unroll
        for (int i = 0; i < 16; ++i) {
            float wsv = 0.0f;
            #pragma unroll
            for (int j = 0; j < 8; ++j) wsv = fmaf(Wr[i*8 + j], utv[j], wsv);
            float p = uniform ? (1.0f / 1152.0f) : pr[i];
            acc[i] = fmaf(p, wsv, acc[i]);
        }
    }
    #pragma unroll
    for (int i = 0; i < 16; ++i)
        sp[(size_t)ch*40960 + ((size_t)c*16 + i)*256 + t] = acc[i];
}

// -------- reduce partials + routing squash over batch axis ------------------
__global__ __launch_bounds__(256) void sreduce_kernel(
        const float* __restrict__ sp, float* __restrict__ obuf) {
    int ci = blockIdx.x;      // 0..159 = c*16+i
    int t  = threadIdx.x;     // b
    float s = 0.0f;
    for (int ch = 0; ch < 72; ++ch) s += sp[(size_t)ch*40960 + (size_t)ci*256 + t];
    float v = s * s;
    #pragma unroll
    for (int m = 1; m < 64; m <<= 1) v += __shfl_xor(v, m, 64);
    __shared__ float red[4];
    if ((t & 63) == 0) red[t >> 6] = v;
    __syncthreads();
    float total = red[0] + red[1] + red[2] + red[3];
    float sc = total / ((1.0f + total) * sqrtf(total));
    obuf[(size_t)ci*256 + t] = sc * s;
}

// -------- delta_b[c,n,i] = sum_b u_hat * outputs ; accumulate into bsum -----
__global__ __launch_bounds__(256) void delta_kernel(
        const float* __restrict__ ut, const float* __restrict__ W,
        const float* __restrict__ obuf, float* __restrict__ bsum, int first) {
    int ch = blockIdx.x;      // 0..35
    int c  = blockIdx.y;      // 0..9
    int t  = threadIdx.x;     // b
    float o16[16];
    #pragma unroll
    for (int i = 0; i < 16; ++i) o16[i] = obuf[((size_t)c*16 + i)*256 + t];
    __shared__ float vbuf[16][257];
    int ri = t >> 4, seg = t & 15;
    int n0 = ch * 32;
    for (int nn = 0; nn < 32; ++nn) {
        int n = n0 + nn;
        float utv[8];
        #pragma unroll
        for (int j = 0; j < 8; ++j) utv[j] = ut[((size_t)n*8 + j)*256 + t];
        const float* Wr = W + ((size_t)c*1152 + n)*128;
        #pragma unroll
        for (int i = 0; i < 16; ++i) {
            float uh = 0.0f;
            #pragma unroll
            for (int j = 0; j < 8; ++j) uh = fmaf(Wr[i*8 + j], utv[j], uh);
            vbuf[i][t] = uh * o16[i];
        }
        __syncthreads();
        float part = 0.0f;
        #pragma unroll
        for (int k = 0; k < 16; ++k) part += vbuf[ri][k*16 + seg];
        #pragma unroll
        for (int m = 1; m < 16; m <<= 1) part += __shfl_xor(part, m, 64);
        if (seg == 0) {
            size_t bi = ((size_t)c*1152 + n)*16 + ri;
            bsum[bi] = first ? part : (bsum[bi] + part);
        }
        __syncthreads();
    }
}

// -------- softmax over the 1152 capsule axis --------------------------------
__global__ __launch_bounds__(256) void softmax_kernel(
        const float* __restrict__ bsum, float* __restrict__ probs) {
    int ci = blockIdx.x;      // c*16+i
    int c = ci >> 4, i = ci & 15;
    int t = threadIdx.x;
    const float* bp = bsum + (size_t)c*1152*16 + i;
    float vals[5];
    float m = -1e30f;
    #pragma unroll
    for (int k = 0; k < 5; ++k) {
        int n = t + k * 256;
        vals[k] = (n < 1152) ? bp[(size_t)n*16] : -1e30f;
        m = fmaxf(m, vals[k]);
    }
    #pragma unroll
    for (int mm = 1; mm < 64; mm <<= 1) m = fmaxf(m, __shfl_xor(m, mm, 64));
    __shared__ float red[4];
    if ((t & 63) == 0) red[t >> 6] = m;
    __syncthreads();
    m = fmaxf(fmaxf(red[0], red[1]), fmaxf(red[2], red[3]));
    __syncthreads();
    float se = 0.0f;
    #pragma unroll
    for (int k = 0; k < 5; ++k) {
        int n = t + k * 256;
        float e = (n < 1152) ? expf(vals[k] - m) : 0.0f;
        vals[k] = e;
        se += e;
    }
    #pragma unroll
    for (int mm = 1; mm < 64; mm <<= 1) se += __shfl_xor(se, mm, 64);
    if ((t & 63) == 0) red[t >> 6] = se;
    __syncthreads();
    se = red[0] + red[1] + red[2] + red[3];
    float inv = 1.0f / se;
    #pragma unroll
    for (int k = 0; k < 5; ++k) {
        int n = t + k * 256;
        if (n < 1152) probs[((size_t)c*1152 + n)*16 + i] = vals[k] * inv;
    }
}

// -------- final: out[b,c] = sum_i outputs[c,i,b]^2 --------------------------
__global__ __launch_bounds__(256) void final_kernel(
        const float* __restrict__ obuf, float* __restrict__ out) {
    int c = blockIdx.x;       // 0..9
    int t = threadIdx.x;      // b
    float s = 0.0f;
    #pragma unroll
    for (int i = 0; i < 16; ++i) {
        float v = obuf[((size_t)c*16 + i)*256 + t];
        s = fmaf(v, v, s);
    }
    out[(size_t)t*10 + c] = s;
}

// ---------------------------------------------------------------------------
extern "C" void kernel_launch(void* const* d_in, const int* in_sizes, int n_in,
                              void* d_out, int out_size, void* d_ws, size_t ws_size,
                              hipStream_t stream) {
    const float* x  = (const float*)d_in[0];
    const float* w1 = (const float*)d_in[1];
    const float* b1 = (const float*)d_in[2];
    const float* w2 = (const float*)d_in[3];
    const float* b2 = (const float*)d_in[4];
    const float* W  = (const float*)d_in[5];
    float* out = (float*)d_out;
    (void)in_sizes; (void)n_in; (void)out_size;

    if (ws_size < B_END) return;

    char* wsb = (char*)d_ws;
    unsigned short* qhi = (unsigned short*)(wsb + B_QHI);
    unsigned short* qlo = (unsigned short*)(wsb + B_QLO);
    unsigned short* whi = (unsigned short*)(wsb + B_WHI);
    unsigned short* wlo = (unsigned short*)(wsb + B_WLO);
    float* h2t = (float*)(wsb + B_H2);
    float* ws = (float*)d_ws;
    float* ut = ws + F_UT;
    float* sp = ws + F_SP;
    float* ob = ws + F_OB;
    float* bs = ws + F_BS;
    float* pr = ws + F_PR;

    w2t_kernel<<<dim3(256, 2), 256, 0, stream>>>(w2, whi, wlo);
    conv1_kernel<<<dim3(256, 2), 256, 0, stream>>>(x, w1, b1, qhi, qlo);
    conv2_mfma<<<dim3(96, 8), 128, 0, stream>>>(qhi, qlo, whi, wlo, b2, h2t);
    squash_t_kernel<<<1152, 256, 0, stream>>>(h2t, ut);

    for (int it = 0; it < 3; ++it) {
        if (it > 0) softmax_kernel<<<160, 256, 0, stream>>>(bs, pr);
        spart_kernel<<<dim3(72, 10), 256, 0, stream>>>(ut, W, pr, sp, it == 0 ? 1 : 0);
        sreduce_kernel<<<160, 256, 0, stream>>>(sp, ob);
        if (it < 2) delta_kernel<<<dim3(36, 10), 256, 0, stream>>>(ut, W, ob, bs, it == 0 ? 1 : 0);
    }
    final_kernel<<<10, 256, 0, stream>>>(ob, out);
}

// Round 6
// 777.425 us; speedup vs baseline: 1.3229x; 1.3229x over previous
//
#include <hip/hip_runtime.h>
#include <math.h>

using short8 = __attribute__((ext_vector_type(8))) short;
using f32x16 = __attribute__((ext_vector_type(16))) float;

// ---------------- workspace byte offsets ----------------
// A2: conv1 out, frag-ordered [qyqx 361][cis 16][b 256][ci16 16] bf16 hi/lo
static const size_t B_QHI = 0;
static const size_t B_QLO = 47316992;
// B2: w2 frag-ordered [k 81][cg 8][cis 16][c 32][ci16 16] bf16 hi/lo
static const size_t B_WHI = 94633984;
static const size_t B_WLO = 105250816;
// h2t (conv2 out, [c*36+p][b] fp32)
static const size_t B_H2  = 115867648;
static const size_t B_END = 125304832;
// routing buffers alias A2 region (dead after conv2) — float offsets
static const size_t F_UT = 0;            // [1152][8][256]
static const size_t F_SP = 2359296;      // [72][160][256]
static const size_t F_OB = 5308416;      // [160][256]
static const size_t F_BS = 5349376;      // [10][1152][16]
static const size_t F_PR = 5533696;      // [10][1152][16]

__device__ __forceinline__ unsigned short bf16_rne(float v) {
    unsigned int u = __builtin_bit_cast(unsigned int, v);
    u += 0x7FFFu + ((u >> 16) & 1u);
    return (unsigned short)(u >> 16);
}
__device__ __forceinline__ float bf16_tof(unsigned short h) {
    unsigned int u = ((unsigned int)h) << 16;
    return __builtin_bit_cast(float, u);
}

// ---------------- conv1: grid (b, x-half), thread = c ----------------------
// writes A2 frag layout: el (qyqx, b, c) -> [(qyqx*16 + c>>4)*256 + b]*16 + (c&15)
__global__ __launch_bounds__(256) void conv1_kernel(
        const float* __restrict__ x, const float* __restrict__ w1,
        const float* __restrict__ b1,
        unsigned short* __restrict__ qhi, unsigned short* __restrict__ qlo) {
    int b  = blockIdx.x;
    int xh = blockIdx.y;                 // 0: ox 0..9, 1: ox 10..18
    int c  = threadIdx.x;
    __shared__ float xs[28][20];
    for (int i = c; i < 560; i += 256) {
        int row = i / 20, cl = i - row * 20, gc = xh * 10 + cl;
        xs[row][cl] = (gc < 28) ? x[(size_t)b*784 + row*28 + gc] : 0.f;
    }
    float wr[81];
    #pragma unroll
    for (int k = 0; k < 81; ++k) wr[k] = w1[c*81 + k];
    float bias = b1[c];
    __syncthreads();
    for (int oy = 0; oy < 19; ++oy) {
        float acc[12];
        #pragma unroll
        for (int e = 0; e < 12; ++e) acc[e] = 0.f;
        #pragma unroll
        for (int ky = 0; ky < 9; ++ky) {
            float xr[20];
            #pragma unroll
            for (int i = 0; i < 20; ++i) xr[i] = xs[oy + ky][i];
            #pragma unroll
            for (int kx = 0; kx < 9; ++kx) {
                float wv_ = wr[ky*9 + kx];
                #pragma unroll
                for (int e = 0; e < 12; ++e)
                    acc[e] = fmaf(xr[e + kx], wv_, acc[e]);
            }
        }
        #pragma unroll
        for (int e = 0; e < 12; ++e) {
            int ox = xh*10 + e;
            if (e < 10 && ox < 19) {
                float v = fmaxf(bias + acc[e], 0.f);
                unsigned short hi = bf16_rne(v);
                unsigned short lo = bf16_rne(v - bf16_tof(hi));
                size_t o = ((size_t)((oy*19 + ox)*16 + (c >> 4))*256 + b)*16 + (c & 15);
                qhi[o] = hi; qlo[o] = lo;
            }
        }
    }
}

// ---------------- w2 -> B2 frag layout ------------------------------------
// B2 el (k, c, ci) -> ((k*8 + c>>5)*16 + ci>>4)*512 + (c&31)*16 + (ci&15)
// per-k block = 8*16*32*16 = 65536 el = 4096 units of 16  (R5 bug: was k*128)
__global__ __launch_bounds__(256) void w2t_kernel(
        const float* __restrict__ w2,
        unsigned short* __restrict__ whi, unsigned short* __restrict__ wlo) {
    int c    = blockIdx.x;
    int half = blockIdx.y;
    int t = threadIdx.x;
    __shared__ float buf[128*81];
    const float* src = w2 + (size_t)c*20736 + (size_t)half*128*81;
    for (int i = t; i < 128*81; i += 256) buf[i] = src[i];
    __syncthreads();
    int kk = t >> 7, cil = t & 127;
    int ci = half*128 + cil;
    size_t cbase = ((size_t)(c >> 5)*16 + (ci >> 4))*32 + (c & 31);
    for (int k2 = 0; k2 < 41; ++k2) {
        int k = k2*2 + kk;
        if (k < 81) {
            float v = buf[cil*81 + k];
            unsigned short hi = bf16_rne(v);
            unsigned short lo = bf16_rne(v - bf16_tof(hi));
            size_t o = (((size_t)k*4096 + cbase)*16) + (ci & 15);
            whi[o] = hi; wlo[o] = lo;
        }
    }
}

// ---------------- conv2: LDS-free, fragment loads direct from L2 ------------
// block = 128 thr = 2 waves (cis halves); tile 32b x 32c x 3ox (oy,oxh fixed).
// Per step (ky, cis): 26 A-frag + 18 B-frag coalesced 1KB chunk loads -> regs,
// 81 MFMA 32x32x16. No barriers in K-loop. Epilogue: LDS reduce + transpose.
__global__ __launch_bounds__(128, 2) void conv2_mfma(
        const unsigned short* __restrict__ qhi, const unsigned short* __restrict__ qlo,
        const unsigned short* __restrict__ whi, const unsigned short* __restrict__ wlo,
        const float* __restrict__ b2, float* __restrict__ h2t) {
    int blk = blockIdx.x;               // 768 blocks, cg fastest (XCD affinity)
    int cg = blk & 7;
    int rest = blk >> 3;
    int oxh = rest & 1; rest >>= 1;
    int oy = rest % 6, bt = rest / 6;   // bt 0..7
    int qx0 = oxh * 6;
    int t = threadIdx.x;
    int wv = t >> 6, l = t & 63;

    // per-lane element offset inside a 512-el fragment chunk
    int loff = (l & 31)*16 + (l >> 5)*8;

    f32x16 acc[3];
    #pragma unroll
    for (int i = 0; i < 3; ++i)
        #pragma unroll
        for (int r = 0; r < 16; ++r) acc[i][r] = 0.f;

    #pragma unroll 1
    for (int ky = 0; ky < 9; ++ky) {
        int qy = oy*2 + ky;
        #pragma unroll 1
        for (int cc = 0; cc < 8; ++cc) {
            int cis = wv*8 + cc;
            short8 afh[13], afl[13], bfh[9], bfl[9];
            size_t abase = (((size_t)(qy*19 + qx0)*16 + cis)*256)*16 + (size_t)bt*512 + loff;
            #pragma unroll
            for (int q = 0; q < 13; ++q) {
                afh[q] = *(const short8*)(qhi + abase + (size_t)q*65536);
                afl[q] = *(const short8*)(qlo + abase + (size_t)q*65536);
            }
            size_t bbase = (((size_t)(ky*9)*8 + cg)*16 + cis)*512 + loff;
            #pragma unroll
            for (int kx = 0; kx < 9; ++kx) {
                bfh[kx] = *(const short8*)(whi + bbase + (size_t)kx*65536);
                bfl[kx] = *(const short8*)(wlo + bbase + (size_t)kx*65536);
            }
            #pragma unroll
            for (int kx = 0; kx < 9; ++kx) {
                #pragma unroll
                for (int oxl = 0; oxl < 3; ++oxl) {
                    int q = 2*oxl + kx;
                    acc[oxl] = __builtin_amdgcn_mfma_f32_32x32x16_bf16(afh[q], bfh[kx], acc[oxl], 0, 0, 0);
                    acc[oxl] = __builtin_amdgcn_mfma_f32_32x32x16_bf16(afh[q], bfl[kx], acc[oxl], 0, 0, 0);
                    acc[oxl] = __builtin_amdgcn_mfma_f32_32x32x16_bf16(afl[q], bfh[kx], acc[oxl], 0, 0, 0);
                }
            }
        }
    }

    __shared__ float smem[3*16*64];      // 12 KB: wave1 partials, then reuse
    // ---- cross-wave reduce (cis halves)
    if (wv == 1) {
        #pragma unroll
        for (int i = 0; i < 3; ++i)
            #pragma unroll
            for (int r = 0; r < 16; ++r)
                smem[(i*16 + r)*64 + l] = acc[i][r];
    }
    __syncthreads();
    if (wv == 0) {
        #pragma unroll
        for (int i = 0; i < 3; ++i)
            #pragma unroll
            for (int r = 0; r < 16; ++r)
                acc[i][r] += smem[(i*16 + r)*64 + l];
    }
    __syncthreads();

    // ---- transpose epilogue via LDS, coalesced float stores
    __shared__ float ebuf[3*1056];       // [3][32 b][33]
    if (wv == 0) {
        float bv = b2[cg*32 + (l & 31)];
        #pragma unroll
        for (int oxl = 0; oxl < 3; ++oxl)
            #pragma unroll
            for (int r = 0; r < 16; ++r) {
                int row = (r & 3) + 8*(r >> 2) + 4*(l >> 5);   // b-local
                ebuf[oxl*1056 + row*33 + (l & 31)] = acc[oxl][r] + bv;
            }
    }
    __syncthreads();
    #pragma unroll 1
    for (int pass = 0; pass < 24; ++pass) {
        int row_id = pass*4 + (t >> 5);          // 0..95 = oxl*32 + c
        int oxl = row_id >> 5, c = row_id & 31;
        float v = ebuf[oxl*1056 + (t & 31)*33 + c];
        int p = oy*6 + oxh*3 + oxl;
        h2t[(size_t)((cg*32 + c)*36 + p)*256 + bt*32 + (t & 31)] = v;
    }
}

// -------- primary squash: h2t[n*8+j][b] -> ut[n][j][b], fully coalesced -----
__global__ __launch_bounds__(256) void squash_t_kernel(
        const float* __restrict__ h2t, float* __restrict__ ut) {
    int n = blockIdx.x;       // 0..1151
    int b = threadIdx.x;      // 0..255
    float v[8];
    float sq = 0.f;
    #pragma unroll
    for (int j = 0; j < 8; ++j) {
        v[j] = h2t[(size_t)(n*8 + j)*256 + b];
        sq = fmaf(v[j], v[j], sq);
    }
    float sc = sq / (1.0f + sq);   // primary squash: NO /sqrt
    #pragma unroll
    for (int j = 0; j < 8; ++j)
        ut[((size_t)n*8 + j)*256 + b] = sc * v[j];
}

// -------- s partials: s[c,i,b] = sum_n probs[c,n,i] * sum_j W*ut ------------
__global__ __launch_bounds__(256) void spart_kernel(
        const float* __restrict__ ut, const float* __restrict__ W,
        const float* __restrict__ probs, float* __restrict__ sp, int uniform) {
    int ch = blockIdx.x;      // 0..71 (n-chunks of 16)
    int c  = blockIdx.y;      // 0..9
    int t  = threadIdx.x;     // b
    float acc[16];
    #pragma unroll
    for (int i = 0; i < 16; ++i) acc[i] = 0.0f;
    int n0 = ch * 16;
    for (int nn = 0; nn < 16; ++nn) {
        int n = n0 + nn;
        float utv[8];
        #pragma unroll
        for (int j = 0; j < 8; ++j) utv[j] = ut[((size_t)n*8 + j)*256 + t];
        const float* Wr = W + ((size_t)c*1152 + n)*128;
        const float* pr = probs + ((size_t)c*1152 + n)*16;
        #pragma unroll
        for (int i = 0; i < 16; ++i) {
            float wsv = 0.0f;
            #pragma unroll
            for (int j = 0; j < 8; ++j) wsv = fmaf(Wr[i*8 + j], utv[j], wsv);
            float p = uniform ? (1.0f / 1152.0f) : pr[i];
            acc[i] = fmaf(p, wsv, acc[i]);
        }
    }
    #pragma unroll
    for (int i = 0; i < 16; ++i)
        sp[(size_t)ch*40960 + ((size_t)c*16 + i)*256 + t] = acc[i];
}

// -------- reduce partials + routing squash over batch axis ------------------
__global__ __launch_bounds__(256) void sreduce_kernel(
        const float* __restrict__ sp, float* __restrict__ obuf) {
    int ci = blockIdx.x;      // 0..159 = c*16+i
    int t  = threadIdx.x;     // b
    float s = 0.0f;
    for (int ch = 0; ch < 72; ++ch) s += sp[(size_t)ch*40960 + (size_t)ci*256 + t];
    float v = s * s;
    #pragma unroll
    for (int m = 1; m < 64; m <<= 1) v += __shfl_xor(v, m, 64);
    __shared__ float red[4];
    if ((t & 63) == 0) red[t >> 6] = v;
    __syncthreads();
    float total = red[0] + red[1] + red[2] + red[3];
    float sc = total / ((1.0f + total) * sqrtf(total));
    obuf[(size_t)ci*256 + t] = sc * s;
}

// -------- delta_b[c,n,i] = sum_b u_hat * outputs ; accumulate into bsum -----
__global__ __launch_bounds__(256) void delta_kernel(
        const float* __restrict__ ut, const float* __restrict__ W,
        const float* __restrict__ obuf, float* __restrict__ bsum, int first) {
    int ch = blockIdx.x;      // 0..71 (n-chunks of 16)
    int c  = blockIdx.y;      // 0..9
    int t  = threadIdx.x;     // b
    float o16[16];
    #pragma unroll
    for (int i = 0; i < 16; ++i) o16[i] = obuf[((size_t)c*16 + i)*256 + t];
    __shared__ float vbuf[16][257];
    int ri = t >> 4, seg = t & 15;
    int n0 = ch * 16;
    for (int nn = 0; nn < 16; ++nn) {
        int n = n0 + nn;
        float utv[8];
        #pragma unroll
        for (int j = 0; j < 8; ++j) utv[j] = ut[((size_t)n*8 + j)*256 + t];
        const float* Wr = W + ((size_t)c*1152 + n)*128;
        #pragma unroll
        for (int i = 0; i < 16; ++i) {
            float uh = 0.0f;
            #pragma unroll
            for (int j = 0; j < 8; ++j) uh = fmaf(Wr[i*8 + j], utv[j], uh);
            vbuf[i][t] = uh * o16[i];
        }
        __syncthreads();
        float part = 0.0f;
        #pragma unroll
        for (int k = 0; k < 16; ++k) part += vbuf[ri][k*16 + seg];
        #pragma unroll
        for (int m = 1; m < 16; m <<= 1) part += __shfl_xor(part, m, 64);
        if (seg == 0) {
            size_t bi = ((size_t)c*1152 + n)*16 + ri;
            bsum[bi] = first ? part : (bsum[bi] + part);
        }
        __syncthreads();
    }
}

// -------- softmax over the 1152 capsule axis --------------------------------
__global__ __launch_bounds__(256) void softmax_kernel(
        const float* __restrict__ bsum, float* __restrict__ probs) {
    int ci = blockIdx.x;      // c*16+i
    int c = ci >> 4, i = ci & 15;
    int t = threadIdx.x;
    const float* bp = bsum + (size_t)c*1152*16 + i;
    float vals[5];
    float m = -1e30f;
    #pragma unroll
    for (int k = 0; k < 5; ++k) {
        int n = t + k * 256;
        vals[k] = (n < 1152) ? bp[(size_t)n*16] : -1e30f;
        m = fmaxf(m, vals[k]);
    }
    #pragma unroll
    for (int mm = 1; mm < 64; mm <<= 1) m = fmaxf(m, __shfl_xor(m, mm, 64));
    __shared__ float red[4];
    if ((t & 63) == 0) red[t >> 6] = m;
    __syncthreads();
    m = fmaxf(fmaxf(red[0], red[1]), fmaxf(red[2], red[3]));
    __syncthreads();
    float se = 0.0f;
    #pragma unroll
    for (int k = 0; k < 5; ++k) {
        int n = t + k * 256;
        float e = (n < 1152) ? expf(vals[k] - m) : 0.0f;
        vals[k] = e;
        se += e;
    }
    #pragma unroll
    for (int mm = 1; mm < 64; mm <<= 1) se += __shfl_xor(se, mm, 64);
    if ((t & 63) == 0) red[t >> 6] = se;
    __syncthreads();
    se = red[0] + red[1] + red[2] + red[3];
    float inv = 1.0f / se;
    #pragma unroll
    for (int k = 0; k < 5; ++k) {
        int n = t + k * 256;
        if (n < 1152) probs[((size_t)c*1152 + n)*16 + i] = vals[k] * inv;
    }
}

// -------- final: out[b,c] = sum_i outputs[c,i,b]^2 --------------------------
__global__ __launch_bounds__(256) void final_kernel(
        const float* __restrict__ obuf, float* __restrict__ out) {
    int c = blockIdx.x;       // 0..9
    int t = threadIdx.x;      // b
    float s = 0.0f;
    #pragma unroll
    for (int i = 0; i < 16; ++i) {
        float v = obuf[((size_t)c*16 + i)*256 + t];
        s = fmaf(v, v, s);
    }
    out[(size_t)t*10 + c] = s;
}

// ---------------------------------------------------------------------------
extern "C" void kernel_launch(void* const* d_in, const int* in_sizes, int n_in,
                              void* d_out, int out_size, void* d_ws, size_t ws_size,
                              hipStream_t stream) {
    const float* x  = (const float*)d_in[0];
    const float* w1 = (const float*)d_in[1];
    const float* b1 = (const float*)d_in[2];
    const float* w2 = (const float*)d_in[3];
    const float* b2 = (const float*)d_in[4];
    const float* W  = (const float*)d_in[5];
    float* out = (float*)d_out;
    (void)in_sizes; (void)n_in; (void)out_size;

    if (ws_size < B_END) return;

    char* wsb = (char*)d_ws;
    unsigned short* qhi = (unsigned short*)(wsb + B_QHI);
    unsigned short* qlo = (unsigned short*)(wsb + B_QLO);
    unsigned short* whi = (unsigned short*)(wsb + B_WHI);
    unsigned short* wlo = (unsigned short*)(wsb + B_WLO);
    float* h2t = (float*)(wsb + B_H2);
    float* ws = (float*)d_ws;
    float* ut = ws + F_UT;
    float* sp = ws + F_SP;
    float* ob = ws + F_OB;
    float* bs = ws + F_BS;
    float* pr = ws + F_PR;

    w2t_kernel<<<dim3(256, 2), 256, 0, stream>>>(w2, whi, wlo);
    conv1_kernel<<<dim3(256, 2), 256, 0, stream>>>(x, w1, b1, qhi, qlo);
    conv2_mfma<<<768, 128, 0, stream>>>(qhi, qlo, whi, wlo, b2, h2t);
    squash_t_kernel<<<1152, 256, 0, stream>>>(h2t, ut);

    for (int it = 0; it < 3; ++it) {
        if (it > 0) softmax_kernel<<<160, 256, 0, stream>>>(bs, pr);
        spart_kernel<<<dim3(72, 10), 256, 0, stream>>>(ut, W, pr, sp, it == 0 ? 1 : 0);
        sreduce_kernel<<<160, 256, 0, stream>>>(sp, ob);
        if (it < 2) delta_kernel<<<dim3(72, 10), 256, 0, stream>>>(ut, W, ob, bs, it == 0 ? 1 : 0);
    }
    final_kernel<<<10, 256, 0, stream>>>(ob, out);
}

// Round 7
// 616.781 us; speedup vs baseline: 1.6674x; 1.2605x over previous
//
#include <hip/hip_runtime.h>
#include <math.h>

using short8 = __attribute__((ext_vector_type(8))) short;
using f32x16 = __attribute__((ext_vector_type(16))) float;

// ---------------- workspace byte offsets ----------------
// A2: conv1 out, frag-ordered [qyqx 361][cis 16][b 256][ci16 16] bf16 hi/lo
static const size_t B_QHI = 0;
static const size_t B_QLO = 47316992;
// B2: w2 frag-ordered [k 81][cg 8][cis 16][c 32][ci16 16] bf16 hi/lo
static const size_t B_WHI = 94633984;
static const size_t B_WLO = 105250816;
// h2t (conv2 out, [c*36+p][b] fp32)
static const size_t B_H2  = 115867648;
static const size_t B_END = 125304832;
// routing buffers alias A2 region (dead after conv2) — float offsets
static const size_t F_UT = 0;            // [1152][8][256]
static const size_t F_SP = 2359296;      // [72][160][256]
static const size_t F_OB = 5308416;      // [160][256]
static const size_t F_BS = 5349376;      // [10][1152][16]
static const size_t F_PR = 5533696;      // [10][1152][16]

__device__ __forceinline__ unsigned short bf16_rne(float v) {
    unsigned int u = __builtin_bit_cast(unsigned int, v);
    u += 0x7FFFu + ((u >> 16) & 1u);
    return (unsigned short)(u >> 16);
}
__device__ __forceinline__ float bf16_tof(unsigned short h) {
    unsigned int u = ((unsigned int)h) << 16;
    return __builtin_bit_cast(float, u);
}

// ---------------- conv1: grid (b, x-half), thread = c ----------------------
// writes A2 frag layout: el (qyqx, b, c) -> [(qyqx*16 + c>>4)*256 + b]*16 + (c&15)
__global__ __launch_bounds__(256) void conv1_kernel(
        const float* __restrict__ x, const float* __restrict__ w1,
        const float* __restrict__ b1,
        unsigned short* __restrict__ qhi, unsigned short* __restrict__ qlo) {
    int b  = blockIdx.x;
    int xh = blockIdx.y;                 // 0: ox 0..9, 1: ox 10..18
    int c  = threadIdx.x;
    __shared__ float xs[28][20];
    for (int i = c; i < 560; i += 256) {
        int row = i / 20, cl = i - row * 20, gc = xh * 10 + cl;
        xs[row][cl] = (gc < 28) ? x[(size_t)b*784 + row*28 + gc] : 0.f;
    }
    float wr[81];
    #pragma unroll
    for (int k = 0; k < 81; ++k) wr[k] = w1[c*81 + k];
    float bias = b1[c];
    __syncthreads();
    for (int oy = 0; oy < 19; ++oy) {
        float acc[12];
        #pragma unroll
        for (int e = 0; e < 12; ++e) acc[e] = 0.f;
        #pragma unroll
        for (int ky = 0; ky < 9; ++ky) {
            float xr[20];
            #pragma unroll
            for (int i = 0; i < 20; ++i) xr[i] = xs[oy + ky][i];
            #pragma unroll
            for (int kx = 0; kx < 9; ++kx) {
                float wv_ = wr[ky*9 + kx];
                #pragma unroll
                for (int e = 0; e < 12; ++e)
                    acc[e] = fmaf(xr[e + kx], wv_, acc[e]);
            }
        }
        #pragma unroll
        for (int e = 0; e < 12; ++e) {
            int ox = xh*10 + e;
            if (e < 10 && ox < 19) {
                float v = fmaxf(bias + acc[e], 0.f);
                unsigned short hi = bf16_rne(v);
                unsigned short lo = bf16_rne(v - bf16_tof(hi));
                size_t o = ((size_t)((oy*19 + ox)*16 + (c >> 4))*256 + b)*16 + (c & 15);
                qhi[o] = hi; qlo[o] = lo;
            }
        }
    }
}

// ---------------- w2 -> B2 frag layout ------------------------------------
// B2 el (k, c, ci) -> ((k*8 + c>>5)*16 + ci>>4)*512 + (c&31)*16 + (ci&15)
__global__ __launch_bounds__(256) void w2t_kernel(
        const float* __restrict__ w2,
        unsigned short* __restrict__ whi, unsigned short* __restrict__ wlo) {
    int c    = blockIdx.x;
    int half = blockIdx.y;
    int t = threadIdx.x;
    __shared__ float buf[128*81];
    const float* src = w2 + (size_t)c*20736 + (size_t)half*128*81;
    for (int i = t; i < 128*81; i += 256) buf[i] = src[i];
    __syncthreads();
    int kk = t >> 7, cil = t & 127;
    int ci = half*128 + cil;
    size_t cbase = ((size_t)(c >> 5)*16 + (ci >> 4))*32 + (c & 31);
    for (int k2 = 0; k2 < 41; ++k2) {
        int k = k2*2 + kk;
        if (k < 81) {
            float v = buf[cil*81 + k];
            unsigned short hi = bf16_rne(v);
            unsigned short lo = bf16_rne(v - bf16_tof(hi));
            size_t o = (((size_t)k*4096 + cbase)*16) + (ci & 15);
            whi[o] = hi; wlo[o] = lo;
        }
    }
}

// ---------------- conv2: LDS-free, XCD-partitioned by batch-tile ------------
// blk = ((oy*2+oxh)*8 + cg)*8 + bt  ->  XCD = blk%8 = bt. Each XCD touches
// only its 32-batch A2 slice; the 8 cg blocks sharing an A-stripe run in
// lockstep on the SAME XCD -> fine-grained L2 reuse.
// block = 256 thr = 4 waves (cis quarters); tile 32b x 32c x 3ox.
__global__ __launch_bounds__(256, 3) void conv2_mfma(
        const unsigned short* __restrict__ qhi, const unsigned short* __restrict__ qlo,
        const unsigned short* __restrict__ whi, const unsigned short* __restrict__ wlo,
        const float* __restrict__ b2, float* __restrict__ h2t) {
    int blk = blockIdx.x;               // 768 blocks
    int bt  = blk & 7;                  // low bits -> XCD partition by batch
    int rest = blk >> 3;
    int cg = rest & 7;
    int oyx = rest >> 3;                // 0..11
    int oxh = oyx & 1, oy = oyx >> 1;
    int qx0 = oxh * 6;
    int t = threadIdx.x;
    int wv = t >> 6, l = t & 63;

    // per-lane element offset inside a 512-el fragment chunk
    int loff = (l & 31)*16 + (l >> 5)*8;

    f32x16 acc[3];
    #pragma unroll
    for (int i = 0; i < 3; ++i)
        #pragma unroll
        for (int r = 0; r < 16; ++r) acc[i][r] = 0.f;

    #pragma unroll 1
    for (int ky = 0; ky < 9; ++ky) {
        int qy = oy*2 + ky;
        #pragma unroll 1
        for (int cc = 0; cc < 4; ++cc) {
            int cis = wv*4 + cc;        // this wave's cis quarter
            short8 afh[13], afl[13], bfh[9], bfl[9];
            size_t abase = (((size_t)(qy*19 + qx0)*16 + cis)*256)*16 + (size_t)bt*512 + loff;
            #pragma unroll
            for (int q = 0; q < 13; ++q) {
                afh[q] = *(const short8*)(qhi + abase + (size_t)q*65536);
                afl[q] = *(const short8*)(qlo + abase + (size_t)q*65536);
            }
            size_t bbase = (((size_t)(ky*9)*8 + cg)*16 + cis)*512 + loff;
            #pragma unroll
            for (int kx = 0; kx < 9; ++kx) {
                bfh[kx] = *(const short8*)(whi + bbase + (size_t)kx*65536);
                bfl[kx] = *(const short8*)(wlo + bbase + (size_t)kx*65536);
            }
            #pragma unroll
            for (int kx = 0; kx < 9; ++kx) {
                #pragma unroll
                for (int oxl = 0; oxl < 3; ++oxl) {
                    int q = 2*oxl + kx;
                    acc[oxl] = __builtin_amdgcn_mfma_f32_32x32x16_bf16(afh[q], bfh[kx], acc[oxl], 0, 0, 0);
                    acc[oxl] = __builtin_amdgcn_mfma_f32_32x32x16_bf16(afh[q], bfl[kx], acc[oxl], 0, 0, 0);
                    acc[oxl] = __builtin_amdgcn_mfma_f32_32x32x16_bf16(afl[q], bfh[kx], acc[oxl], 0, 0, 0);
                }
            }
        }
    }

    // ---- cross-wave reduce (cis quarters): waves 1..3 dump, wave0 sums ----
    __shared__ float red[3][3][16][64];    // 36,864 B
    if (wv >= 1) {
        #pragma unroll
        for (int i = 0; i < 3; ++i)
            #pragma unroll
            for (int r = 0; r < 16; ++r)
                red[wv-1][i][r][l] = acc[i][r];
    }
    __syncthreads();
    if (wv == 0) {
        #pragma unroll
        for (int i = 0; i < 3; ++i)
            #pragma unroll
            for (int r = 0; r < 16; ++r)
                acc[i][r] += red[0][i][r][l] + red[1][i][r][l] + red[2][i][r][l];
    }

    // ---- transpose epilogue via LDS, coalesced float stores
    __shared__ float ebuf[3*1056];         // [3][32 b][33] = 12,672 B
    if (wv == 0) {
        float bv = b2[cg*32 + (l & 31)];
        #pragma unroll
        for (int oxl = 0; oxl < 3; ++oxl)
            #pragma unroll
            for (int r = 0; r < 16; ++r) {
                int row = (r & 3) + 8*(r >> 2) + 4*(l >> 5);   // b-local
                ebuf[oxl*1056 + row*33 + (l & 31)] = acc[oxl][r] + bv;
            }
    }
    __syncthreads();
    #pragma unroll 1
    for (int pass = 0; pass < 12; ++pass) {
        int row_id = pass*8 + (t >> 5);          // 0..95 = oxl*32 + c
        int oxl = row_id >> 5, c = row_id & 31;
        float v = ebuf[oxl*1056 + (t & 31)*33 + c];
        int p = oy*6 + oxh*3 + oxl;
        h2t[(size_t)((cg*32 + c)*36 + p)*256 + bt*32 + (t & 31)] = v;
    }
}

// -------- primary squash: h2t[n*8+j][b] -> ut[n][j][b], fully coalesced -----
__global__ __launch_bounds__(256) void squash_t_kernel(
        const float* __restrict__ h2t, float* __restrict__ ut) {
    int n = blockIdx.x;       // 0..1151
    int b = threadIdx.x;      // 0..255
    float v[8];
    float sq = 0.f;
    #pragma unroll
    for (int j = 0; j < 8; ++j) {
        v[j] = h2t[(size_t)(n*8 + j)*256 + b];
        sq = fmaf(v[j], v[j], sq);
    }
    float sc = sq / (1.0f + sq);   // primary squash: NO /sqrt
    #pragma unroll
    for (int j = 0; j < 8; ++j)
        ut[((size_t)n*8 + j)*256 + b] = sc * v[j];
}

// -------- s partials: s[c,i,b] = sum_n probs[c,n,i] * sum_j W*ut ------------
__global__ __launch_bounds__(256) void spart_kernel(
        const float* __restrict__ ut, const float* __restrict__ W,
        const float* __restrict__ probs, float* __restrict__ sp, int uniform) {
    int ch = blockIdx.x;      // 0..71 (n-chunks of 16)
    int c  = blockIdx.y;      // 0..9
    int t  = threadIdx.x;     // b
    float acc[16];
    #pragma unroll
    for (int i = 0; i < 16; ++i) acc[i] = 0.0f;
    int n0 = ch * 16;
    for (int nn = 0; nn < 16; ++nn) {
        int n = n0 + nn;
        float utv[8];
        #pragma unroll
        for (int j = 0; j < 8; ++j) utv[j] = ut[((size_t)n*8 + j)*256 + t];
        const float* Wr = W + ((size_t)c*1152 + n)*128;
        const float* pr = probs + ((size_t)c*1152 + n)*16;
        #pragma unroll
        for (int i = 0; i < 16; ++i) {
            float wsv = 0.0f;
            #pragma unroll
            for (int j = 0; j < 8; ++j) wsv = fmaf(Wr[i*8 + j], utv[j], wsv);
            float p = uniform ? (1.0f / 1152.0f) : pr[i];
            acc[i] = fmaf(p, wsv, acc[i]);
        }
    }
    #pragma unroll
    for (int i = 0; i < 16; ++i)
        sp[(size_t)ch*40960 + ((size_t)c*16 + i)*256 + t] = acc[i];
}

// -------- reduce partials + routing squash over batch axis ------------------
__global__ __launch_bounds__(256) void sreduce_kernel(
        const float* __restrict__ sp, float* __restrict__ obuf) {
    int ci = blockIdx.x;      // 0..159 = c*16+i
    int t  = threadIdx.x;     // b
    float s = 0.0f;
    for (int ch = 0; ch < 72; ++ch) s += sp[(size_t)ch*40960 + (size_t)ci*256 + t];
    float v = s * s;
    #pragma unroll
    for (int m = 1; m < 64; m <<= 1) v += __shfl_xor(v, m, 64);
    __shared__ float red[4];
    if ((t & 63) == 0) red[t >> 6] = v;
    __syncthreads();
    float total = red[0] + red[1] + red[2] + red[3];
    float sc = total / ((1.0f + total) * sqrtf(total));
    obuf[(size_t)ci*256 + t] = sc * s;
}

// -------- delta_b[c,n,i] = sum_b u_hat * outputs ; accumulate into bsum -----
__global__ __launch_bounds__(256) void delta_kernel(
        const float* __restrict__ ut, const float* __restrict__ W,
        const float* __restrict__ obuf, float* __restrict__ bsum, int first) {
    int ch = blockIdx.x;      // 0..71 (n-chunks of 16)
    int c  = blockIdx.y;      // 0..9
    int t  = threadIdx.x;     // b
    float o16[16];
    #pragma unroll
    for (int i = 0; i < 16; ++i) o16[i] = obuf[((size_t)c*16 + i)*256 + t];
    __shared__ float vbuf[16][257];
    int ri = t >> 4, seg = t & 15;
    int n0 = ch * 16;
    for (int nn = 0; nn < 16; ++nn) {
        int n = n0 + nn;
        float utv[8];
        #pragma unroll
        for (int j = 0; j < 8; ++j) utv[j] = ut[((size_t)n*8 + j)*256 + t];
        const float* Wr = W + ((size_t)c*1152 + n)*128;
        #pragma unroll
        for (int i = 0; i < 16; ++i) {
            float uh = 0.0f;
            #pragma unroll
            for (int j = 0; j < 8; ++j) uh = fmaf(Wr[i*8 + j], utv[j], uh);
            vbuf[i][t] = uh * o16[i];
        }
        __syncthreads();
        float part = 0.0f;
        #pragma unroll
        for (int k = 0; k < 16; ++k) part += vbuf[ri][k*16 + seg];
        #pragma unroll
        for (int m = 1; m < 16; m <<= 1) part += __shfl_xor(part, m, 64);
        if (seg == 0) {
            size_t bi = ((size_t)c*1152 + n)*16 + ri;
            bsum[bi] = first ? part : (bsum[bi] + part);
        }
        __syncthreads();
    }
}

// -------- softmax over the 1152 capsule axis --------------------------------
__global__ __launch_bounds__(256) void softmax_kernel(
        const float* __restrict__ bsum, float* __restrict__ probs) {
    int ci = blockIdx.x;      // c*16+i
    int c = ci >> 4, i = ci & 15;
    int t = threadIdx.x;
    const float* bp = bsum + (size_t)c*1152*16 + i;
    float vals[5];
    float m = -1e30f;
    #pragma unroll
    for (int k = 0; k < 5; ++k) {
        int n = t + k * 256;
        vals[k] = (n < 1152) ? bp[(size_t)n*16] : -1e30f;
        m = fmaxf(m, vals[k]);
    }
    #pragma unroll
    for (int mm = 1; mm < 64; mm <<= 1) m = fmaxf(m, __shfl_xor(m, mm, 64));
    __shared__ float red[4];
    if ((t & 63) == 0) red[t >> 6] = m;
    __syncthreads();
    m = fmaxf(fmaxf(red[0], red[1]), fmaxf(red[2], red[3]));
    __syncthreads();
    float se = 0.0f;
    #pragma unroll
    for (int k = 0; k < 5; ++k) {
        int n = t + k * 256;
        float e = (n < 1152) ? expf(vals[k] - m) : 0.0f;
        vals[k] = e;
        se += e;
    }
    #pragma unroll
    for (int mm = 1; mm < 64; mm <<= 1) se += __shfl_xor(se, mm, 64);
    if ((t & 63) == 0) red[t >> 6] = se;
    __syncthreads();
    se = red[0] + red[1] + red[2] + red[3];
    float inv = 1.0f / se;
    #pragma unroll
    for (int k = 0; k < 5; ++k) {
        int n = t + k * 256;
        if (n < 1152) probs[((size_t)c*1152 + n)*16 + i] = vals[k] * inv;
    }
}

// -------- final: out[b,c] = sum_i outputs[c,i,b]^2 --------------------------
__global__ __launch_bounds__(256) void final_kernel(
        const float* __restrict__ obuf, float* __restrict__ out) {
    int c = blockIdx.x;       // 0..9
    int t = threadIdx.x;      // b
    float s = 0.0f;
    #pragma unroll
    for (int i = 0; i < 16; ++i) {
        float v = obuf[((size_t)c*16 + i)*256 + t];
        s = fmaf(v, v, s);
    }
    out[(size_t)t*10 + c] = s;
}

// ---------------------------------------------------------------------------
extern "C" void kernel_launch(void* const* d_in, const int* in_sizes, int n_in,
                              void* d_out, int out_size, void* d_ws, size_t ws_size,
                              hipStream_t stream) {
    const float* x  = (const float*)d_in[0];
    const float* w1 = (const float*)d_in[1];
    const float* b1 = (const float*)d_in[2];
    const float* w2 = (const float*)d_in[3];
    const float* b2 = (const float*)d_in[4];
    const float* W  = (const float*)d_in[5];
    float* out = (float*)d_out;
    (void)in_sizes; (void)n_in; (void)out_size;

    if (ws_size < B_END) return;

    char* wsb = (char*)d_ws;
    unsigned short* qhi = (unsigned short*)(wsb + B_QHI);
    unsigned short* qlo = (unsigned short*)(wsb + B_QLO);
    unsigned short* whi = (unsigned short*)(wsb + B_WHI);
    unsigned short* wlo = (unsigned short*)(wsb + B_WLO);
    float* h2t = (float*)(wsb + B_H2);
    float* ws = (float*)d_ws;
    float* ut = ws + F_UT;
    float* sp = ws + F_SP;
    float* ob = ws + F_OB;
    float* bs = ws + F_BS;
    float* pr = ws + F_PR;

    w2t_kernel<<<dim3(256, 2), 256, 0, stream>>>(w2, whi, wlo);
    conv1_kernel<<<dim3(256, 2), 256, 0, stream>>>(x, w1, b1, qhi, qlo);
    conv2_mfma<<<768, 256, 0, stream>>>(qhi, qlo, whi, wlo, b2, h2t);
    squash_t_kernel<<<1152, 256, 0, stream>>>(h2t, ut);

    for (int it = 0; it < 3; ++it) {
        if (it > 0) softmax_kernel<<<160, 256, 0, stream>>>(bs, pr);
        spart_kernel<<<dim3(72, 10), 256, 0, stream>>>(ut, W, pr, sp, it == 0 ? 1 : 0);
        sreduce_kernel<<<160, 256, 0, stream>>>(sp, ob);
        if (it < 2) delta_kernel<<<dim3(72, 10), 256, 0, stream>>>(ut, W, ob, bs, it == 0 ? 1 : 0);
    }
    final_kernel<<<10, 256, 0, stream>>>(ob, out);
}